// Round 7
// baseline (163.677 us; speedup 1.0000x reference)
//
#include <hip/hip_runtime.h>
#include <stdint.h>

#define B 8
#define N 1000
#define C 91
#define NC 90            // classes minus background
#define D 1024
#define KMAX 2048        // NMS_TOPK
#define PAD 4096         // key slots/image: 4*N=4000 used (<=4 classes/row can have softmax>0.2), rest zero
#define DETS 36
#define SCORE_THRESH 0.2f
#define NMS_THRESH 0.5f
#define MIN_SIZE 0.01f
#define XFORM_CLIP 4.135166556742356f   // log(1000/16)
#define NBLK 256         // 1 block/CU: co-residency structurally guaranteed (2 fit/CU)
#define NTHR 512

// ---- decode, bit-identical to all prior passing rounds ----
__device__ __forceinline__ void decode_clip(const float* __restrict__ rg,
                                            float wdt, float hgt, float cx, float cy,
                                            float W, float H,
                                            float& x1, float& y1, float& x2, float& y2) {
    float dx = rg[0] / 10.0f;
    float dy = rg[1] / 10.0f;
    float dw = fminf(rg[2] / 5.0f, XFORM_CLIP);
    float dh = fminf(rg[3] / 5.0f, XFORM_CLIP);
    float pcx = dx * wdt + cx;
    float pcy = dy * hgt + cy;
    float pw  = expf(dw) * wdt;
    float ph  = expf(dh) * hgt;
    x1 = fminf(fmaxf(pcx - 0.5f * pw, 0.0f), W);
    y1 = fminf(fmaxf(pcy - 0.5f * ph, 0.0f), H);
    x2 = fminf(fmaxf(pcx + 0.5f * pw, 0.0f), W);
    y2 = fminf(fmaxf(pcy + 0.5f * ph, 0.0f), H);
}

// ---- software grid barrier (ROCm CG pattern). Counters memset to 0 on the
// stream before launch; one counter per barrier use (monotonic, no reuse).
__device__ __forceinline__ void gridbar(int* cnt) {
    __syncthreads();
    if (threadIdx.x == 0) {
        __threadfence();                       // release block's global writes
        atomicAdd(cnt, 1);                     // device-scope arrive
        while (atomicAdd(cnt, 0) < NBLK)       // device-scope spin load
            __builtin_amdgcn_s_sleep(2);       // throttle L2 atomic traffic
        __threadfence();                       // acquire
    }
    __syncthreads();
}

__global__ __launch_bounds__(NTHR) void k_fused(
        const float* __restrict__ logits, const float* __restrict__ reg,
        const float* __restrict__ props,  const int* __restrict__ img_hw,
        const float* __restrict__ feats,  float* __restrict__ out,
        int* __restrict__ bar, unsigned long long* __restrict__ keys,
        int* __restrict__ Kvals,
        float* __restrict__ bx1, float* __restrict__ by1,
        float* __restrict__ bx2, float* __restrict__ by2,
        int* __restrict__ propn) {

    __shared__ union {
        unsigned long long slot[8][4];                                   // phase 1
        struct { unsigned long long sk[PAD]; int partial[8][128]; } p2;  // phase 2 (36 KB)
        struct { float kx1[DETS], ky1[DETS], kx2[DETS], ky2[DETS];
                 int kpn[DETS]; int skept; } p3;                         // phase 3
    } sm;

    int g = blockIdx.x;
    int w = threadIdx.x >> 6, lane = threadIdx.x & 63;

    // ================= phase 1: score (wave per row, 4 rows/wave) =================
    for (int i = 0; i < 4; ++i) {
        int r = (g * 8 + w) * 4 + i;
        if (r < B * N) {
            int b = r / N, n = r % N;
            if (lane < 4) sm.slot[w][lane] = 0ULL;        // same-wave LDS, no barrier

            const float* lg = logits + (size_t)r * C;
            float v0 = lg[lane];
            float v1 = (lane < C - 64) ? lg[64 + lane] : -3.4e38f;
            float m = fmaxf(v0, v1);
            #pragma unroll
            for (int off = 32; off; off >>= 1) m = fmaxf(m, __shfl_xor(m, off, 64));
            float e0 = expf(v0 - m);
            float e1 = (lane < C - 64) ? expf(v1 - m) : 0.0f;
            float s = e0 + e1;
            #pragma unroll
            for (int off = 32; off; off >>= 1) s += __shfl_xor(s, off, 64);

            float p0 = props[r * 4 + 0], p1 = props[r * 4 + 1];
            float p2 = props[r * 4 + 2], p3 = props[r * 4 + 3];
            float wdt = p2 - p0, hgt = p3 - p1;
            float cx = p0 + 0.5f * wdt, cy = p1 + 0.5f * hgt;
            float H = (float)img_hw[b * 2 + 0];
            float W = (float)img_hw[b * 2 + 1];

            unsigned long long keyv[2] = {0ULL, 0ULL};
            #pragma unroll
            for (int t2 = 0; t2 < 2; ++t2) {
                int c = lane + t2 * 64;
                float e = t2 ? e1 : e0;
                if (c >= 1 && c < C) {
                    float sc = e / s;
                    if (sc > SCORE_THRESH) {
                        const float* rg = reg + (size_t)r * (C * 4) + (size_t)c * 4;
                        float x1, y1, x2, y2;
                        decode_clip(rg, wdt, hgt, cx, cy, W, H, x1, y1, x2, y2);
                        if ((x2 - x1) >= MIN_SIZE && (y2 - y1) >= MIN_SIZE) {
                            unsigned int idx = (unsigned int)(n * NC + (c - 1));
                            keyv[t2] = ((unsigned long long)__float_as_uint(sc) << 32) |
                                       (unsigned long long)(0xFFFFFFFFu - idx);
                        }
                    }
                }
            }
            unsigned long long m0 = __ballot(keyv[0] != 0ULL);
            unsigned long long m1 = __ballot(keyv[1] != 0ULL);
            unsigned long long lower = (1ULL << lane) - 1ULL;
            if (keyv[0]) sm.slot[w][__popcll(m0 & lower)] = keyv[0];
            if (keyv[1]) sm.slot[w][__popcll(m0) + __popcll(m1 & lower)] = keyv[1];
            if (lane < 4)
                keys[(size_t)b * PAD + (size_t)n * 4 + lane] = sm.slot[w][lane];
        }
    }

    gridbar(&bar[0]);

    // ================= phase 2: rank-and-scatter (32 blocks/image) =================
    {
        int b = g >> 5, sub = g & 31;
        const unsigned long long* kb = keys + (size_t)b * PAD;
        for (int t = threadIdx.x; t < PAD; t += NTHR)
            sm.p2.sk[t] = (t < 4 * N) ? kb[t] : 0ULL;   // zero never outranks a valid key
        __syncthreads();

        int rbase = sub * 128;                 // block's 128 rows
        unsigned long long my0 = sm.p2.sk[rbase + lane];
        unsigned long long my1 = sm.p2.sk[rbase + lane + 64];
        int c0 = 0, c1 = 0;
        int base = w * 512;                    // wave's 512-key slice (wave-uniform)
        #pragma unroll 8
        for (int it = 0; it < 512; ++it) {
            unsigned long long k = sm.p2.sk[base + it];   // broadcast read
            c0 += (k > my0) ? 1 : 0;
            c1 += (k > my1) ? 1 : 0;
        }
        sm.p2.partial[w][lane]      = c0;
        sm.p2.partial[w][lane + 64] = c1;
        __syncthreads();

        if (threadIdx.x < 128) {
            int rl = threadIdx.x;
            int rank = 0;
            #pragma unroll
            for (int q = 0; q < 8; ++q) rank += sm.p2.partial[q][rl];
            int row = rbase + rl;
            unsigned long long my = sm.p2.sk[row];
            if (row == 4 * N) Kvals[b] = (rank < KMAX) ? rank : KMAX;  // rank of zero key == V_valid
            if (my != 0ULL && rank < KMAX) {
                unsigned int idx = 0xFFFFFFFFu - (unsigned int)(my & 0xFFFFFFFFull);
                int n = (int)(idx / NC);
                int c = (int)(idx % NC) + 1;
                int r = b * N + n;
                float p0 = props[r * 4 + 0], p1 = props[r * 4 + 1];
                float p2 = props[r * 4 + 2], p3 = props[r * 4 + 3];
                float wdt = p2 - p0, hgt = p3 - p1;
                float cx = p0 + 0.5f * wdt, cy = p1 + 0.5f * hgt;
                float H = (float)img_hw[b * 2 + 0];
                float W = (float)img_hw[b * 2 + 1];
                const float* rg = reg + (size_t)r * (C * 4) + (size_t)c * 4;
                float x1, y1, x2, y2;
                decode_clip(rg, wdt, hgt, cx, cy, W, H, x1, y1, x2, y2);
                size_t o = (size_t)b * KMAX + rank;
                bx1[o] = x1; by1[o] = y1; bx2[o] = x2; by2[o] = y2;
                propn[o] = n;
            }
        }
    }

    gridbar(&bar[1]);
    if (g >= B) return;                        // barrier satisfied; extra blocks retire

    // ================= phase 3: greedy NMS (wave 0 of blocks 0..7) =================
    int b = g;
    if (threadIdx.x < 64) {
        int K = Kvals[b];
        size_t ofs = (size_t)b * KMAX;
        int kept = 0;
        for (int cs = 0; cs < K && kept < DETS; cs += 64) {
            int j = cs + lane;
            bool inr = (j < K);
            int jj = inr ? j : 0;
            float x1 = bx1[ofs + jj], y1 = by1[ofs + jj];
            float x2 = bx2[ofs + jj], y2 = by2[ofs + jj];
            int pn = propn[ofs + jj];
            float area = (x2 - x1) * (y2 - y1);

            bool supp = !inr;
            for (int k = 0; k < kept; ++k) {
                float c1 = sm.p3.kx1[k], c2 = sm.p3.ky1[k];
                float c3 = sm.p3.kx2[k], c4 = sm.p3.ky2[k];
                float carea = (c3 - c1) * (c4 - c2);
                float ix1 = fmaxf(c1, x1), iy1 = fmaxf(c2, y1);
                float ix2 = fminf(c3, x2), iy2 = fminf(c4, y2);
                float iw = fmaxf(ix2 - ix1, 0.0f), ih = fmaxf(iy2 - iy1, 0.0f);
                float inter = iw * ih;
                float uni = carea + area - inter;
                float iou = (uni > 0.0f) ? (inter / uni) : 0.0f;
                supp = supp || (iou > NMS_THRESH);
            }
            unsigned long long live = __ballot(!supp);
            while (live != 0ULL && kept < DETS) {
                int i = __ffsll((unsigned long long)live) - 1;
                float c1 = __shfl(x1, i, 64), c2 = __shfl(y1, i, 64);
                float c3 = __shfl(x2, i, 64), c4 = __shfl(y2, i, 64);
                int   cp = __shfl(pn, i, 64);
                if (lane == 0) { sm.p3.kx1[kept] = c1; sm.p3.ky1[kept] = c2;
                                 sm.p3.kx2[kept] = c3; sm.p3.ky2[kept] = c4;
                                 sm.p3.kpn[kept] = cp; }
                kept++;
                float carea = (c3 - c1) * (c4 - c2);
                float ix1 = fmaxf(c1, x1), iy1 = fmaxf(c2, y1);
                float ix2 = fminf(c3, x2), iy2 = fminf(c4, y2);
                float iw = fmaxf(ix2 - ix1, 0.0f), ih = fmaxf(iy2 - iy1, 0.0f);
                float inter = iw * ih;
                float uni = carea + area - inter;
                float iou = (uni > 0.0f) ? (inter / iou == iou ? uni : uni) : 0.0f; // (see below)
                iou = (uni > 0.0f) ? (inter / uni) : 0.0f;
                live &= ~__ballot(iou > NMS_THRESH);   // clears bit i too (self IoU=1)
            }
        }
        if (lane == 0) sm.p3.skept = kept;
    }
    __syncthreads();

    // ================= phase 4: gather (512 threads, 2 slots in flight) ===========
    int kept = sm.p3.skept;
    int half = threadIdx.x >> 8;               // 0 or 1
    int t = threadIdx.x & 255;                 // float4 index within row
    const float4* f4 = (const float4*)feats;
    float4* o4 = (float4*)out;
    for (int s = half; s < DETS; s += 2) {
        float4 v = make_float4(0.f, 0.f, 0.f, 0.f);
        if (s < kept) v = f4[((size_t)b * N + sm.p3.kpn[s]) * (D / 4) + t];
        o4[((size_t)b * DETS + s) * (D / 4) + t] = v;
    }
}

extern "C" void kernel_launch(void* const* d_in, const int* in_sizes, int n_in,
                              void* d_out, int out_size, void* d_ws, size_t ws_size,
                              hipStream_t stream) {
    const float* logits = (const float*)d_in[0];   // [B,N,C]
    const float* reg    = (const float*)d_in[1];   // [B,N,C*4]
    const float* props  = (const float*)d_in[2];   // [B,N,4]
    const float* feats  = (const float*)d_in[3];   // [B,N,D]
    const int*   img    = (const int*)d_in[4];     // [B,2]
    float* out = (float*)d_out;                    // [B,DETS,D]

    char* ws = (char*)d_ws;
    int* bar     = (int*)(ws + 0);                 // 2 barrier counters (memset below)
    int* Kvals   = (int*)(ws + 128);               // 8 ints
    unsigned long long* keys = (unsigned long long*)(ws + 4096);   // 8*4096 u64 = 256KB
    float* bx1 = (float*)(ws + 270336);            // each 8*2048*4 = 64KB
    float* by1 = (float*)(ws + 335872);
    float* bx2 = (float*)(ws + 401408);
    float* by2 = (float*)(ws + 466944);
    int*   propn = (int*)(ws + 532480);

    hipMemsetAsync(bar, 0, 64, stream);
    k_fused<<<dim3(NBLK), dim3(NTHR), 0, stream>>>(
        logits, reg, props, img, feats, out,
        bar, keys, Kvals, bx1, by1, bx2, by2, propn);
}

// Round 8
// 115.009 us; speedup vs baseline: 1.4232x; 1.4232x over previous
//
#include <hip/hip_runtime.h>
#include <stdint.h>

#define B 8
#define N 1000
#define C 91
#define NC 90            // classes minus background
#define D 1024
#define KMAX 2048        // NMS_TOPK
#define PAD 4096         // key slots/image: 4*N=4000 used (<=4 classes/row can have softmax>0.2), rest zero
#define DETS 36
#define SCORE_THRESH 0.2f
#define NMS_THRESH 0.5f
#define MIN_SIZE 0.01f
#define XFORM_CLIP 4.135166556742356f   // log(1000/16)

// ---- decode, bit-identical across all kernels and rounds ----
__device__ __forceinline__ void decode_clip(const float* __restrict__ rg,
                                            float wdt, float hgt, float cx, float cy,
                                            float W, float H,
                                            float& x1, float& y1, float& x2, float& y2) {
    float dx = rg[0] / 10.0f;
    float dy = rg[1] / 10.0f;
    float dw = fminf(rg[2] / 5.0f, XFORM_CLIP);
    float dh = fminf(rg[3] / 5.0f, XFORM_CLIP);
    float pcx = dx * wdt + cx;
    float pcy = dy * hgt + cy;
    float pw  = expf(dw) * wdt;
    float ph  = expf(dh) * hgt;
    x1 = fminf(fmaxf(pcx - 0.5f * pw, 0.0f), W);
    y1 = fminf(fmaxf(pcy - 0.5f * ph, 0.0f), H);
    x2 = fminf(fmaxf(pcx + 0.5f * pw, 0.0f), W);
    y2 = fminf(fmaxf(pcy + 0.5f * ph, 0.0f), H);
}

// ---- kernel 1: wave-per-row class-parallel softmax + decode + filter.
// Fixed slots keys[n*4+p] via ballot compaction; no atomics, no memset.
// (unchanged from R5/R6 — ~31 waves/CU, latency well hidden)
__global__ __launch_bounds__(256) void k_score(const float* __restrict__ logits,
                        const float* __restrict__ reg,
                        const float* __restrict__ props,
                        const int* __restrict__ img_hw,
                        unsigned long long* __restrict__ keys) {
    int b = blockIdx.x / 250;            // 250 blocks per image, 4 rows per block
    int local = blockIdx.x % 250;
    int wib = threadIdx.x >> 6, lane = threadIdx.x & 63;
    int n = local * 4 + wib;
    int r = b * N + n;

    __shared__ unsigned long long slot[4][4];
    if (threadIdx.x < 16) slot[threadIdx.x >> 2][threadIdx.x & 3] = 0ULL;
    __syncthreads();

    const float* lg = logits + (size_t)r * C;
    float v0 = lg[lane];                                   // classes 0..63
    float v1 = (lane < C - 64) ? lg[64 + lane] : -3.4e38f; // classes 64..90
    float m = fmaxf(v0, v1);
    #pragma unroll
    for (int off = 32; off; off >>= 1) m = fmaxf(m, __shfl_xor(m, off, 64));
    float e0 = expf(v0 - m);
    float e1 = (lane < C - 64) ? expf(v1 - m) : 0.0f;
    float s = e0 + e1;
    #pragma unroll
    for (int off = 32; off; off >>= 1) s += __shfl_xor(s, off, 64);

    float p0 = props[r * 4 + 0], p1 = props[r * 4 + 1];
    float p2 = props[r * 4 + 2], p3 = props[r * 4 + 3];
    float wdt = p2 - p0, hgt = p3 - p1;
    float cx = p0 + 0.5f * wdt, cy = p1 + 0.5f * hgt;
    float H = (float)img_hw[b * 2 + 0];
    float W = (float)img_hw[b * 2 + 1];

    unsigned long long keyv[2] = {0ULL, 0ULL};
    #pragma unroll
    for (int t2 = 0; t2 < 2; ++t2) {
        int c = lane + t2 * 64;
        float e = t2 ? e1 : e0;
        if (c >= 1 && c < C) {
            float sc = e / s;
            if (sc > SCORE_THRESH) {
                const float* rg = reg + (size_t)r * (C * 4) + (size_t)c * 4;
                float x1, y1, x2, y2;
                decode_clip(rg, wdt, hgt, cx, cy, W, H, x1, y1, x2, y2);
                if ((x2 - x1) >= MIN_SIZE && (y2 - y1) >= MIN_SIZE) {
                    unsigned int idx = (unsigned int)(n * NC + (c - 1));
                    keyv[t2] = ((unsigned long long)__float_as_uint(sc) << 32) |
                               (unsigned long long)(0xFFFFFFFFu - idx);
                }
            }
        }
    }
    unsigned long long m0 = __ballot(keyv[0] != 0ULL);
    unsigned long long m1 = __ballot(keyv[1] != 0ULL);
    unsigned long long lower = (1ULL << lane) - 1ULL;
    if (keyv[0]) slot[wib][__popcll(m0 & lower)] = keyv[0];
    if (keyv[1]) slot[wib][__popcll(m0) + __popcll(m1 & lower)] = keyv[1];
    __syncthreads();
    if (threadIdx.x < 16) {
        int ww = threadIdx.x >> 2, p = threadIdx.x & 3;
        keys[(size_t)b * PAD + (size_t)(local * 4 + ww) * 4 + p] = slot[ww][p];
    }
}

// ---- kernel 2: rank-and-scatter (R7 phase-2 inner loop, standalone).
// sorted pos == #{keys > mine} (keys unique; zeros rank last). 32 blocks/image
// x 512 threads: block ranks 128 rows (2 register keys/lane); each of its 8
// waves scans a 512-key slice via wave-uniform broadcast LDS reads (1 read
// feeds 128 compares). Partials combined in LDS; winners decode + scatter.
// Row 4*N is always zero-keyed: its rank == V_valid -> writes Kvals for free.
__global__ __launch_bounds__(512) void k_rank(int* __restrict__ Kvals,
                                              const unsigned long long* __restrict__ keys,
                                              const float* __restrict__ reg,
                                              const float* __restrict__ props,
                                              const int* __restrict__ img_hw,
                                              float* __restrict__ bx1, float* __restrict__ by1,
                                              float* __restrict__ bx2, float* __restrict__ by2,
                                              int* __restrict__ propn) {
    __shared__ unsigned long long sk[PAD];   // 32 KB
    __shared__ int partial[8][128];
    int b = blockIdx.y, sub = blockIdx.x;
    const unsigned long long* kb = keys + (size_t)b * PAD;
    for (int t = threadIdx.x; t < PAD; t += 512)
        sk[t] = (t < 4 * N) ? kb[t] : 0ULL;  // zero never outranks a valid key
    __syncthreads();

    int w = threadIdx.x >> 6, lane = threadIdx.x & 63;
    int rbase = sub * 128;                   // block's 128 rows
    unsigned long long my0 = sk[rbase + lane];
    unsigned long long my1 = sk[rbase + lane + 64];
    int c0 = 0, c1 = 0;
    int base = w * 512;                      // wave's 512-key slice (wave-uniform)
    #pragma unroll 8
    for (int it = 0; it < 512; ++it) {
        unsigned long long k = sk[base + it];    // broadcast read
        c0 += (k > my0) ? 1 : 0;
        c1 += (k > my1) ? 1 : 0;
    }
    partial[w][lane]      = c0;
    partial[w][lane + 64] = c1;
    __syncthreads();

    if (threadIdx.x < 128) {
        int rl = threadIdx.x;
        int rank = 0;
        #pragma unroll
        for (int q = 0; q < 8; ++q) rank += partial[q][rl];
        int row = rbase + rl;
        unsigned long long my = sk[row];
        if (row == 4 * N) Kvals[b] = (rank < KMAX) ? rank : KMAX;  // rank of zero key == V_valid
        if (my != 0ULL && rank < KMAX) {
            unsigned int idx = 0xFFFFFFFFu - (unsigned int)(my & 0xFFFFFFFFull);
            int n = (int)(idx / NC);
            int c = (int)(idx % NC) + 1;
            int r = b * N + n;
            float p0 = props[r * 4 + 0], p1 = props[r * 4 + 1];
            float p2 = props[r * 4 + 2], p3 = props[r * 4 + 3];
            float wdt = p2 - p0, hgt = p3 - p1;
            float cx = p0 + 0.5f * wdt, cy = p1 + 0.5f * hgt;
            float H = (float)img_hw[b * 2 + 0];
            float W = (float)img_hw[b * 2 + 1];
            const float* rg = reg + (size_t)r * (C * 4) + (size_t)c * 4;
            float x1, y1, x2, y2;
            decode_clip(rg, wdt, hgt, cx, cy, W, H, x1, y1, x2, y2);
            size_t o = (size_t)b * KMAX + rank;
            bx1[o] = x1; by1[o] = y1; bx2[o] = x2; by2[o] = y2;
            propn[o] = n;
        }
    }
}

// ---- kernel 3: greedy NMS, one wave per image (R5 version, proven 4 µs).
// Suppression flows only from kept (<=36): per 64-chunk, check vs kept list,
// then pop lowest live rank via ffsll+shfl broadcast; early exit at 36.
__global__ __launch_bounds__(64) void k_nms(const int* __restrict__ Kvals,
                                            const float* __restrict__ bx1, const float* __restrict__ by1,
                                            const float* __restrict__ bx2, const float* __restrict__ by2,
                                            const int* __restrict__ propn,
                                            int* __restrict__ sel) {
    __shared__ float kx1[DETS], ky1[DETS], kx2[DETS], ky2[DETS];
    __shared__ int kpn[DETS];
    int b = blockIdx.x, lane = threadIdx.x;
    int K = Kvals[b];
    size_t ofs = (size_t)b * KMAX;
    int kept = 0;

    for (int cs = 0; cs < K && kept < DETS; cs += 64) {
        int j = cs + lane;
        bool inr = (j < K);
        int jj = inr ? j : 0;
        float x1 = bx1[ofs + jj], y1 = by1[ofs + jj];
        float x2 = bx2[ofs + jj], y2 = by2[ofs + jj];
        int pn = propn[ofs + jj];
        float area = (x2 - x1) * (y2 - y1);

        bool supp = !inr;
        for (int k = 0; k < kept; ++k) {
            float c1 = kx1[k], c2 = ky1[k], c3 = kx2[k], c4 = ky2[k];
            float carea = (c3 - c1) * (c4 - c2);
            float ix1 = fmaxf(c1, x1), iy1 = fmaxf(c2, y1);
            float ix2 = fminf(c3, x2), iy2 = fminf(c4, y2);
            float iw = fmaxf(ix2 - ix1, 0.0f), ih = fmaxf(iy2 - iy1, 0.0f);
            float inter = iw * ih;
            float uni = carea + area - inter;
            float iou = (uni > 0.0f) ? (inter / uni) : 0.0f;
            supp = supp || (iou > NMS_THRESH);
        }
        unsigned long long live = __ballot(!supp);
        while (live != 0ULL && kept < DETS) {
            int i = __ffsll((unsigned long long)live) - 1;
            float c1 = __shfl(x1, i, 64), c2 = __shfl(y1, i, 64);
            float c3 = __shfl(x2, i, 64), c4 = __shfl(y2, i, 64);
            int   cp = __shfl(pn, i, 64);
            if (lane == 0) { kx1[kept] = c1; ky1[kept] = c2; kx2[kept] = c3; ky2[kept] = c4; kpn[kept] = cp; }
            kept++;
            float carea = (c3 - c1) * (c4 - c2);
            float ix1 = fmaxf(c1, x1), iy1 = fmaxf(c2, y1);
            float ix2 = fminf(c3, x2), iy2 = fminf(c4, y2);
            float iw = fmaxf(ix2 - ix1, 0.0f), ih = fmaxf(iy2 - iy1, 0.0f);
            float inter = iw * ih;
            float uni = carea + area - inter;
            float iou = (uni > 0.0f) ? (inter / uni) : 0.0f;
            live &= ~__ballot(iou > NMS_THRESH);     // clears bit i too (self IoU=1)
        }
    }
    __syncthreads();                                  // single wave: orders LDS writes
    if (lane < DETS) sel[b * DETS + lane] = (lane < kept) ? kpn[lane] : -1;
}

// ---- kernel 4: gather feature rows (or zeros), 288 parallel blocks (R5) ----
__global__ __launch_bounds__(256) void k_gather(const int* __restrict__ sel,
                                                const float* __restrict__ feats,
                                                float* __restrict__ out) {
    int slot = blockIdx.x;            // b*DETS + s
    int b = slot / DETS;
    int row = sel[slot];
    float4* o = (float4*)(out + (size_t)slot * D);
    if (row >= 0) {
        const float4* f = (const float4*)(feats + ((size_t)b * N + row) * D);
        o[threadIdx.x] = f[threadIdx.x];
    } else {
        o[threadIdx.x] = make_float4(0.f, 0.f, 0.f, 0.f);
    }
}

extern "C" void kernel_launch(void* const* d_in, const int* in_sizes, int n_in,
                              void* d_out, int out_size, void* d_ws, size_t ws_size,
                              hipStream_t stream) {
    const float* logits = (const float*)d_in[0];   // [B,N,C]
    const float* reg    = (const float*)d_in[1];   // [B,N,C*4]
    const float* props  = (const float*)d_in[2];   // [B,N,4]
    const float* feats  = (const float*)d_in[3];   // [B,N,D]
    const int*   img    = (const int*)d_in[4];     // [B,2]
    float* out = (float*)d_out;                    // [B,DETS,D]

    char* ws = (char*)d_ws;
    int* Kvals    = (int*)(ws + 0);                        // 8 ints (written unconditionally by k_rank)
    int* sel      = (int*)(ws + 256);                      // 8*36 ints (fully written by k_nms)
    unsigned long long* keys = (unsigned long long*)(ws + 4096);      // 8*4096 u64 = 256KB (fully written by k_score)
    float* bx1 = (float*)(ws + 270336);                    // each 8*2048*4 = 64KB (ranks >= K guarded)
    float* by1 = (float*)(ws + 335872);
    float* bx2 = (float*)(ws + 401408);
    float* by2 = (float*)(ws + 466944);
    int*   propn = (int*)(ws + 532480);

    k_score<<<dim3(B * 250), dim3(256), 0, stream>>>(logits, reg, props, img, keys);
    k_rank<<<dim3(32, B), dim3(512), 0, stream>>>(Kvals, keys,
        reg, props, img, bx1, by1, bx2, by2, propn);
    k_nms<<<dim3(B), dim3(64), 0, stream>>>(Kvals, bx1, by1, bx2, by2, propn, sel);
    k_gather<<<dim3(B * DETS), dim3(256), 0, stream>>>(sel, feats, out);
}